// Round 3
// baseline (455.563 us; speedup 1.0000x reference)
//
#include <hip/hip_runtime.h>

#define B_ 8
#define C_ 256
#define H_ 128
#define W_ 128
#define NW_ 512
#define HW_ (H_*W_)
#define EPS_ 1e-5f

typedef __attribute__((ext_vector_type(8))) short bf16x8;
typedef __attribute__((ext_vector_type(4))) float f32x4;

// RNE float -> bf16
__device__ __forceinline__ unsigned short f2bf(float f) {
  unsigned u = __float_as_uint(f);
  u += 0x7fffu + ((u >> 16) & 1u);
  return (unsigned short)(u >> 16);
}
__device__ __forceinline__ float bf2f(unsigned short h) {
  return __uint_as_float(((unsigned)h) << 16);
}
__device__ __forceinline__ float bflo(unsigned u){ return __uint_as_float(u << 16); }
__device__ __forceinline__ float bfhi(unsigned u){ return __uint_as_float(u & 0xffff0000u); }

// ---------- BN stats stage 1: 32 segments x 256 channels ----------
__global__ __launch_bounds__(256)
void bn_partial(const float* __restrict__ x, float* __restrict__ psum,
                float* __restrict__ psq) {
  const int seg = blockIdx.x;            // 0..31: b = seg>>2, quarter = seg&3
  const int c   = blockIdx.y;
  const int tid = threadIdx.x;
  const float4* p = (const float4*)(x + (size_t)((seg >> 2)*C_ + c)*HW_ + (seg & 3)*4096);
  float s = 0.f, s2 = 0.f;
  #pragma unroll
  for (int i = 0; i < 4; ++i) {
    float4 v = p[tid + i*256];
    s  += v.x + v.y + v.z + v.w;
    s2 += v.x*v.x + v.y*v.y + v.z*v.z + v.w*v.w;
  }
  #pragma unroll
  for (int off = 32; off > 0; off >>= 1) {
    s  += __shfl_down(s, off);
    s2 += __shfl_down(s2, off);
  }
  __shared__ float rs[4], rq[4];
  if ((tid & 63) == 0) { rs[tid >> 6] = s; rq[tid >> 6] = s2; }
  __syncthreads();
  if (tid == 0) {
    psum[c*32 + seg] = rs[0]+rs[1]+rs[2]+rs[3];
    psq [c*32 + seg] = rq[0]+rq[1]+rq[2]+rq[3];
  }
}

// ---------- BN stats stage 2 ----------
__global__ __launch_bounds__(256)
void bn_final(float* __restrict__ wsf, const float* __restrict__ gamma,
              const float* __restrict__ beta) {
  const int c = threadIdx.x;
  float S = 0.f, S2 = 0.f;
  #pragma unroll
  for (int j = 0; j < 32; ++j) {
    S  += wsf[512 + c*32 + j];
    S2 += wsf[512 + 8192 + c*32 + j];
  }
  const float n = (float)(B_*HW_);
  float mean = S / n;
  float var  = S2 / n - mean*mean;
  float scl  = gamma[c] * rsqrtf(var + EPS_);
  wsf[c]      = scl;
  wsf[C_ + c] = beta[c] - mean*scl;
}

// ---------- w1 -> bf16 A-fragment table ----------
// frag[(mtG*16 + ks)*64 + lane][j] = w1[mtG*16 + (lane&15)][ks*32 + (lane>>4)*8 + j]
__global__ __launch_bounds__(64)
void w1prep(const float* __restrict__ w1, ushort* __restrict__ w1f) {
  const int l15 = threadIdx.x & 15, quad = threadIdx.x >> 4;
  const int mtG = blockIdx.x >> 4, ks = blockIdx.x & 15;
  const float* src = w1 + (size_t)(mtG*16 + l15)*NW_ + ks*32 + quad*8;
  float4 f0 = *(const float4*)src, f1 = *(const float4*)(src + 4);
  union { unsigned u[4]; uint4 q; } cv;
  cv.u[0] = (unsigned)f2bf(f0.x) | ((unsigned)f2bf(f0.y) << 16);
  cv.u[1] = (unsigned)f2bf(f0.z) | ((unsigned)f2bf(f0.w) << 16);
  cv.u[2] = (unsigned)f2bf(f1.x) | ((unsigned)f2bf(f1.y) << 16);
  cv.u[3] = (unsigned)f2bf(f1.z) | ((unsigned)f2bf(f1.w) << 16);
  ((uint4*)w1f)[blockIdx.x*64 + threadIdx.x] = cv.q;
}

// ---------- fused: BN-apply + dw3x3 + relu + 1x1 (MFMA) + bias + residual ----------
// grid (W/16, H/4, B) = 2048 blocks, 256 threads (4 waves).
// 8 K-chunks of 32 in-ch / 64 y-ch (K=64). LDS = 21.5 KB. Register-prefetched staging.
template<bool PREW1>
__global__ __launch_bounds__(256, 3)
void fused_mfma(const float* __restrict__ x, const float* __restrict__ lbpw,
                const float* __restrict__ w1raw, const ushort* __restrict__ w1f,
                const float* __restrict__ b1, const float* __restrict__ sc_sh,
                float* __restrict__ out) {
  const int tid  = threadIdx.x;
  const int b    = blockIdx.z;
  const int h0   = blockIdx.y * 4;
  const int w0   = blockIdx.x * 16;
  const int wave = tid >> 6;
  const int lane = tid & 63;
  const int l15  = lane & 15;
  const int quad = lane >> 4;
  const int cl   = tid >> 3;   // 0..31: staged channel-lane AND dwconv input channel
  const int sub  = tid & 7;    // staging col-lane / dwconv col-group

  __shared__ __align__(16) ushort s_xn[32][6][24];  // normalized bf16, pitch 24 (2-way banks)
  __shared__ __align__(16) ushort s_yT[64][72];     // y [px][o_local], pitch 72 (=4 words mod 32)
  __shared__ __align__(16) float  s_wc[64][12];     // lbp weights chunk

  f32x4 acc[4][4];
  #pragma unroll
  for (int mt = 0; mt < 4; ++mt)
    #pragma unroll
    for (int nt = 0; nt < 4; ++nt) {
      f32x4 z = {0.f, 0.f, 0.f, 0.f};
      acc[mt][nt] = z;
    }

  // register-prefetch state for one 32-channel chunk
  float pv[6][3];
  float psc, psh;
  auto prefetch = [&](int k) {
    const int ch = k*32 + cl;
    psc = sc_sh[ch];
    psh = sc_sh[C_ + ch];
    const float* bp = x + (size_t)(b*C_ + ch) * HW_;
    #pragma unroll
    for (int r = 0; r < 6; ++r) {
      const int h = h0 + r - 1;
      #pragma unroll
      for (int s = 0; s < 3; ++s) {
        const int c = sub + s*8;
        const int w = w0 + c - 1;
        const bool ok = (h >= 0) && (h < H_) && (c < 18) && (w >= 0) && (w < W_);
        pv[r][s] = ok ? bp[h*W_ + w] : 0.f;
      }
    }
  };

  prefetch(0);

  #pragma unroll 1
  for (int k = 0; k < 8; ++k) {
    if (k) __syncthreads();   // prev GEMM done with s_yT, prev dwconv done with s_xn/s_wc

    // ---- write prefetched chunk into LDS (division-free) ----
    #pragma unroll
    for (int r = 0; r < 6; ++r) {
      const int h = h0 + r - 1;
      const bool hv = (h >= 0) && (h < H_);
      #pragma unroll
      for (int s = 0; s < 3; ++s) {
        const int c = sub + s*8;
        if (c < 18) {
          const int w = w0 + c - 1;
          const bool ok = hv && (w >= 0) && (w < W_);
          s_xn[cl][r][c] = ok ? f2bf(fmaf(pv[r][s], psc, psh)) : (ushort)0;
        }
      }
    }
    // stage lbp weights: 64 o x 9 floats; thread tid>>2 stages 3 at col 3*(tid&3)
    {
      const int oo = tid >> 2, j0 = 3*(tid & 3);
      if (j0 < 9) {
        const float* wp = lbpw + (size_t)(k*64 + oo)*9 + j0;
        s_wc[oo][j0]   = wp[0];
        s_wc[oo][j0+1] = wp[1];
        s_wc[oo][j0+2] = wp[2];
      }
    }
    __syncthreads();          // s_xn / s_wc ready

    if (k < 7) prefetch(k + 1);   // global loads in flight across dwconv+GEMM

    // ---- depthwise 3x3 + relu -> s_yT ----
    {
      float v[6][4];
      #pragma unroll
      for (int r = 0; r < 6; ++r) {
        const unsigned u0 = *(const unsigned*)&s_xn[cl][r][2*sub];
        const unsigned u1 = *(const unsigned*)&s_xn[cl][r][2*sub + 2];
        v[r][0] = bflo(u0); v[r][1] = bfhi(u0);
        v[r][2] = bflo(u1); v[r][3] = bfhi(u1);
      }
      const float4 wa0 = *(const float4*)&s_wc[2*cl][0];
      const float4 wa1 = *(const float4*)&s_wc[2*cl][4];
      const float  wa8 = s_wc[2*cl][8];
      const float4 wb0 = *(const float4*)&s_wc[2*cl + 1][0];
      const float4 wb1 = *(const float4*)&s_wc[2*cl + 1][4];
      const float  wb8 = s_wc[2*cl + 1][8];
      const float wA[9] = {wa0.x, wa0.y, wa0.z, wa0.w, wa1.x, wa1.y, wa1.z, wa1.w, wa8};
      const float wB[9] = {wb0.x, wb0.y, wb0.z, wb0.w, wb1.x, wb1.y, wb1.z, wb1.w, wb8};
      #pragma unroll
      for (int r = 0; r < 4; ++r) {
        float y0[2] = {0.f, 0.f}, y1[2] = {0.f, 0.f};
        #pragma unroll
        for (int di = 0; di < 3; ++di)
          #pragma unroll
          for (int dj = 0; dj < 3; ++dj) {
            const float wa = wA[di*3 + dj], wb = wB[di*3 + dj];
            #pragma unroll
            for (int cc = 0; cc < 2; ++cc) {
              const float t = v[r + di][dj + cc];
              y0[cc] = fmaf(wa, t, y0[cc]);
              y1[cc] = fmaf(wb, t, y1[cc]);
            }
          }
        #pragma unroll
        for (int cc = 0; cc < 2; ++cc) {
          const unsigned pk = (unsigned)f2bf(fmaxf(y0[cc], 0.f)) |
                              ((unsigned)f2bf(fmaxf(y1[cc], 0.f)) << 16);
          *(unsigned*)&s_yT[r*16 + 2*sub + cc][2*cl] = pk;
        }
      }
    }
    __syncthreads();          // s_yT ready

    // ---- GEMM: K=64 = two K32 MFMA steps ----
    #pragma unroll
    for (int ks = 0; ks < 2; ++ks) {
      bf16x8 bfr[4];
      #pragma unroll
      for (int nt = 0; nt < 4; ++nt)
        bfr[nt] = *(const bf16x8*)&s_yT[nt*16 + l15][ks*32 + quad*8];
      #pragma unroll
      for (int mt = 0; mt < 4; ++mt) {
        bf16x8 afr;
        if constexpr (PREW1) {
          union { uint4 q; bf16x8 v; } cv;
          cv.q = *(const uint4*)(w1f + (size_t)(((wave*4 + mt)*16 + (k*2 + ks))*64 + lane)*8);
          afr = cv.v;
        } else {
          const float* wp = w1raw + (size_t)(wave*64 + mt*16 + l15)*NW_ + k*64 + ks*32 + quad*8;
          const float4 f0 = *(const float4*)wp;
          const float4 f1 = *(const float4*)(wp + 4);
          union { unsigned u[4]; bf16x8 v; } cv;
          cv.u[0] = (unsigned)f2bf(f0.x) | ((unsigned)f2bf(f0.y) << 16);
          cv.u[1] = (unsigned)f2bf(f0.z) | ((unsigned)f2bf(f0.w) << 16);
          cv.u[2] = (unsigned)f2bf(f1.x) | ((unsigned)f2bf(f1.y) << 16);
          cv.u[3] = (unsigned)f2bf(f1.z) | ((unsigned)f2bf(f1.w) << 16);
          afr = cv.v;
        }
        #pragma unroll
        for (int nt = 0; nt < 4; ++nt)
          acc[mt][nt] = __builtin_amdgcn_mfma_f32_16x16x32_bf16(afr, bfr[nt], acc[mt][nt], 0, 0, 0);
      }
    }
  }

  // ---- epilogue: + b1 + raw-x residual (coalesced global re-read, exact) ----
  #pragma unroll
  for (int mt = 0; mt < 4; ++mt) {
    #pragma unroll
    for (int nt = 0; nt < 4; ++nt) {
      const int h = h0 + nt;
      #pragma unroll
      for (int i = 0; i < 4; ++i) {
        const int ch = wave*64 + mt*16 + quad*4 + i;
        const size_t idx = ((size_t)(b*C_ + ch)*H_ + h)*W_ + w0 + l15;
        out[idx] = acc[mt][nt][i] + b1[ch] + x[idx];
      }
    }
  }
}

extern "C" void kernel_launch(void* const* d_in, const int* in_sizes, int n_in,
                              void* d_out, int out_size, void* d_ws, size_t ws_size,
                              hipStream_t stream) {
  const float* x     = (const float*)d_in[0];
  const float* gamma = (const float*)d_in[1];
  const float* beta  = (const float*)d_in[2];
  const float* lbpw  = (const float*)d_in[3];
  const float* w1    = (const float*)d_in[4];
  const float* b1    = (const float*)d_in[5];
  float* out = (float*)d_out;

  // ws floats: [0,256) scale | [256,512) shift | [512,8704) psum | [8704,16896) psq
  // byte 69632: w1 bf16 fragment table (256 KB)
  float* wsf  = (float*)d_ws;
  ushort* w1f = (ushort*)((char*)d_ws + 69632);
  const bool pre = ws_size >= (size_t)(69632 + 262144);

  bn_partial<<<dim3(32, C_), 256, 0, stream>>>(x, wsf + 512, wsf + 512 + 8192);
  bn_final<<<1, 256, 0, stream>>>(wsf, gamma, beta);

  dim3 grid(W_/16, H_/4, B_);
  if (pre) {
    w1prep<<<256, 64, 0, stream>>>(w1, w1f);
    fused_mfma<true><<<grid, 256, 0, stream>>>(x, lbpw, w1, w1f, b1, wsf, out);
  } else {
    fused_mfma<false><<<grid, 256, 0, stream>>>(x, lbpw, w1, w1f, b1, wsf, out);
  }
}